// Round 14
// baseline (183.458 us; speedup 1.0000x reference)
//
#include <hip/hip_runtime.h>
#include <math.h>
#include <stdint.h>

// Problem: ProcessFeatures_83296595738632
// corr[bs,bg,i] = sum_{h,j,k} sat[bs,h,(i+j)%64,k] * grd[bg,h,j,15-k]
// orien = argmax_i corr (first-max); dot with cyclic shift orien, /||sat||
// distance[bg,bs] = 2-2*dot[bs,bg]; out: sat | grd | distance | orien(float)
//
// R14: corr on mfma_f32_32x32x16_bf16 (R6-hardware-verified layouts), grid
// (3 nt3 x 96 bs x 4 kz) = 1152 blocks x 256 thr, 33 KB LDS -> 4 blocks/CU.
// Epilogue fused via last-block-done atomic (threadfence + counter per tile,
// counters zeroed by pack each launch). Norms precomputed in pack.

#define BS   96
#define H    4
#define W    64
#define C    16
#define BG   96
#define HWC  (H*W*C)                  // 4096

#define SAT_ELEMS (BS*H*W*C)          // 393216
#define OUT_DIST  (2*SAT_ELEMS)       // 786432
#define OUT_ORIEN (OUT_DIST + BS*BG)  // 795648

#define NT3       3
#define TILE_CNT  (BS*NT3)            // 288

#define WS_PART_OFF  ((size_t)2 * SAT_ELEMS * 2)                 // 1.5 MB (Bpk)
#define WS_NORM_OFF  (WS_PART_OFF + (size_t)TILE_CNT * 4 * 2048 * 4)  // +9.4 MB
#define WS_CNT_OFF   (WS_NORM_OFF + 512)
#define WS_NEEDED    (WS_CNT_OFF + (size_t)TILE_CNT * 4)

typedef __attribute__((ext_vector_type(4)))  short short4v;
typedef __attribute__((ext_vector_type(8)))  short short8v;
typedef __attribute__((ext_vector_type(16))) float f32x16;

__device__ __forceinline__ void bsplit(float x, unsigned short& hi, unsigned short& lo) {
    unsigned int u = __float_as_uint(x);
    unsigned int r = (u + 0x7FFFu + ((u >> 16) & 1u)) >> 16;   // RNE to bf16
    hi = (unsigned short)r;
    float hf = __uint_as_float(r << 16);
    float l = x - hf;
    unsigned int ul = __float_as_uint(l);
    unsigned int rl = (ul + 0x7FFFu + ((ul >> 16) & 1u)) >> 16;
    lo = (unsigned short)rl;
}

// ---------------- prologue: pack B fragments (32x32x16 layout), norms,
//                  zero tile counters, passthrough copies ----------------
// Fragment f = ((j*4 + kh)*3 + nt3): lane l, elem e ->
//   B[k16 = (l>>5)*8+e][col = l&31] of K-slice hk = kh*16+k16, col group nt3
//   = grdR[j][nt3*32 + (l&31)][kh*16 + (l>>5)*8 + e]
//   grdR[j][bg][hk] = grd[bg][hk>>4][j][15-(hk&15)];  h = kh.
__global__ __launch_bounds__(512)
void pf_pack_b(const float* __restrict__ sat, const float* __restrict__ grd,
               unsigned short* __restrict__ Bpk, float* __restrict__ norms,
               unsigned int* __restrict__ cnt, float* __restrict__ out)
{
    __shared__ float nred[8];
    const int tid = threadIdx.x;
    const int t = blockIdx.x * 512 + tid;      // < 49152 = 768 frag * 64 lanes

    // ---- fragment packing ----
    {
        int lane = t & 63;
        int f    = t >> 6;            // < 768
        int nt3  = f % 3;
        int g    = f / 3;
        int kh   = g & 3;
        int j    = g >> 2;
        int col  = nt3 * 32 + (lane & 31);
        int k0   = (lane >> 5) * 8;

        const float* row = grd + ((size_t)(col * 4 + kh) * 64 + j) * 16 + (8 - k0);
        float tmp[8];
        *(float4*)&tmp[0] = *(const float4*)(row);
        *(float4*)&tmp[4] = *(const float4*)(row + 4);

        short8v hv, lv;
        #pragma unroll
        for (int e = 0; e < 8; ++e) {
            unsigned short hi, lo;
            bsplit(tmp[7 - e], hi, lo);      // value[e] = grd[...][15-k0-e]
            hv[e] = (short)hi; lv[e] = (short)lo;
        }
        size_t base = (size_t)f << 10;       // 1024 ushorts per fragment pair
        *(short8v*)&Bpk[base + lane * 8]       = hv;   // hi plane
        *(short8v*)&Bpk[base + 512 + lane * 8] = lv;   // lo plane
    }

    // ---- zero tile counters (global t < 288 -> block 0) ----
    if (t < TILE_CNT) cnt[t] = 0u;

    // ---- norm of sat[bs = blockIdx.x] ----
    {
        const int wv = tid >> 6, lane = tid & 63;
        float np = 0.f;
        const float4* sb = (const float4*)(sat + (size_t)blockIdx.x * HWC);
        #pragma unroll
        for (int x = tid; x < 1024; x += 512) {
            float4 v = sb[x];
            np = fmaf(v.x, v.x, fmaf(v.y, v.y, fmaf(v.z, v.z, fmaf(v.w, v.w, np))));
        }
        #pragma unroll
        for (int off = 32; off; off >>= 1) np += __shfl_xor(np, off);
        if (lane == 0) nred[wv] = np;
        __syncthreads();
        if (tid == 0) {
            float s = ((nred[0] + nred[1]) + (nred[2] + nred[3]))
                    + ((nred[4] + nred[5]) + (nred[6] + nred[7]));
            norms[blockIdx.x] = sqrtf(s + 1e-8f);
        }
    }

    // ---- passthrough copies: out[0..] = sat, out[SAT..] = grd ----
    {
        const float4* s4 = (const float4*)sat;
        const float4* g4 = (const float4*)grd;
        float4* o4 = (float4*)out;
        #pragma unroll
        for (int idx = t; idx < 2 * SAT_ELEMS / 4; idx += 49152) {
            o4[idx] = (idx < SAT_ELEMS / 4) ? s4[idx] : g4[idx - SAT_ELEMS / 4];
        }
    }
}

// ---------------- corr (32x32x16 MFMA) + fused last-block epilogue ----------
#define MFMA32(a, b, c) __builtin_amdgcn_mfma_f32_32x32x16_bf16((a), (b), (c), 0, 0, 0)

__global__ __launch_bounds__(256, 4)
void pf_corr(const float* __restrict__ sat, const float* __restrict__ grd,
             const unsigned short* __restrict__ Bpk, float* __restrict__ part,
             const float* __restrict__ norms, unsigned int* __restrict__ cnt,
             float* __restrict__ out)
{
    __shared__ unsigned short sHi[4096], sLo[4096];   // satM planes, swizzled (16 KB)
    __shared__ float corrPart[2][64][33];             // 16.9 KB
    __shared__ int   orienL[32];
    __shared__ int   lastFlag;

    const int nt3 = blockIdx.x;          // 32-bg group
    const int bs  = blockIdx.y;
    const int kz  = blockIdx.z;          // K quarter: j in [kz*16, kz*16+16)
    const int tid = threadIdx.x;
    const int wv  = tid >> 6, lane = tid & 63;
    const int l31 = lane & 31, u = lane >> 5;

    // ---- stage satM (swizzled bf16 hi/lo) ----
    // satM[w][hk] = sat[bs][hk>>4][w][hk&15]; chunk cc=hk>>3 at slot cc^(w&7)
    {
        const float4* satB = (const float4*)(sat + (size_t)bs * HWC);
        #pragma unroll
        for (int x = tid; x < 1024; x += 256) {
            float4 v = satB[x];
            int e = 4 * x;
            int h = e >> 10, w = (e >> 4) & 63, k = e & 15;
            int cc = (h * 16 + k) >> 3;
            int dst = w * 64 + ((cc ^ (w & 7)) * 8) + (k & 7);
            short4v hvv, lvv;
            unsigned short hi, lo;
            bsplit(v.x, hi, lo); hvv[0] = hi; lvv[0] = lo;
            bsplit(v.y, hi, lo); hvv[1] = hi; lvv[1] = lo;
            bsplit(v.z, hi, lo); hvv[2] = hi; lvv[2] = lo;
            bsplit(v.w, hi, lo); hvv[3] = hi; lvv[3] = lo;
            *(short4v*)&sHi[dst] = hvv;
            *(short4v*)&sLo[dst] = lvv;
        }
    }
    __syncthreads();

    // ---- corr GEMM: bf16x4, 2 mtiles (M 0-31 / 32-63), K-slice 4 j per wave ----
    f32x16 accL, accH;
    #pragma unroll
    for (int i = 0; i < 16; ++i) { accL[i] = 0.f; accH[i] = 0.f; }

    const unsigned short* __restrict__ bb = Bpk + ((size_t)nt3 << 10) + lane * 8;
    // ushort strides: per kh = 3<<10, per j = 12<<10

    #pragma unroll
    for (int jj = 0; jj < 4; ++jj) {
        const int j = kz * 16 + wv * 4 + jj;
        const unsigned short* bj = bb + (size_t)j * (12 << 10);
        #pragma unroll
        for (int kh = 0; kh < 4; ++kh) {
            const unsigned short* bp = bj + (size_t)kh * (3 << 10);
            short8v bh = *(const short8v*)bp;
            short8v bl = *(const short8v*)(bp + 512);
            const int cc = kh * 2 + u;
            // mtile 0: rows (l31 + j) & 63
            {
                const int r = (l31 + j) & 63;
                const int aoff = (r << 6) + ((cc ^ (r & 7)) << 3);
                short8v ah = *(const short8v*)&sHi[aoff];
                short8v al = *(const short8v*)&sLo[aoff];
                accL = MFMA32(ah, bh, accL);
                accL = MFMA32(ah, bl, accL);
                accL = MFMA32(al, bh, accL);
                accL = MFMA32(al, bl, accL);
            }
            // mtile 1: rows (32 + l31 + j) & 63
            {
                const int r = (32 + l31 + j) & 63;
                const int aoff = (r << 6) + ((cc ^ (r & 7)) << 3);
                short8v ah = *(const short8v*)&sHi[aoff];
                short8v al = *(const short8v*)&sLo[aoff];
                accH = MFMA32(ah, bh, accH);
                accH = MFMA32(ah, bl, accH);
                accH = MFMA32(al, bh, accH);
                accH = MFMA32(al, bl, accH);
            }
        }
    }

    // ---- C/D -> corrPart, two-phase reduce (waves 0,1 write; 2,3 add) ----
    // C/D: col = lane&31, row = (reg&3)+8*(reg>>2)+4*(lane>>5) [R6-verified]
    if (wv < 2) {
        #pragma unroll
        for (int reg = 0; reg < 16; ++reg) {
            int row = (reg & 3) + 8 * (reg >> 2) + 4 * u;
            corrPart[wv][row][l31]      = accL[reg];
            corrPart[wv][32 + row][l31] = accH[reg];
        }
    }
    __syncthreads();
    if (wv >= 2) {
        #pragma unroll
        for (int reg = 0; reg < 16; ++reg) {
            int row = (reg & 3) + 8 * (reg >> 2) + 4 * u;
            corrPart[wv - 2][row][l31]      += accL[reg];
            corrPart[wv - 2][32 + row][l31] += accH[reg];
        }
    }
    __syncthreads();

    // ---- write partial slice (2048 f32, coalesced) ----
    const int tile = bs * NT3 + nt3;
    float* dst = part + ((size_t)(tile * 4 + kz) << 11);
    #pragma unroll
    for (int e = tid; e < 2048; e += 256) {
        const int row = e >> 5, col = e & 31;
        dst[e] = corrPart[0][row][col] + corrPart[1][row][col];
    }

    // ---- last-block-done gate ----
    __threadfence();
    if (tid == 0) lastFlag = (atomicAdd(&cnt[tile], 1u) == 3u) ? 1 : 0;
    __syncthreads();
    if (!lastFlag) return;
    __threadfence();

    // ================= fused epilogue (one block per tile) =================
    // sum the 4 kz partials into corrE (reuse corrPart[0] storage, [64][33])
    float* corrE = &corrPart[0][0][0];
    {
        const float* p0 = part + ((size_t)(tile * 4) << 11);
        #pragma unroll
        for (int e = tid; e < 2048; e += 256) {
            const int row = e >> 5, col = e & 31;
            corrE[row * 33 + col] = (p0[e] + p0[2048 + e]) + (p0[4096 + e] + p0[6144 + e]);
        }
    }
    __syncthreads();

    // argmax per bg (first-max tie-break): wave wv -> bgc = wv*8..+7
    #pragma unroll
    for (int t = 0; t < 8; ++t) {
        const int bgc = wv * 8 + t;
        float v = corrE[lane * 33 + bgc];
        int idx = lane;
        #pragma unroll
        for (int off = 32; off; off >>= 1) {
            float ov = __shfl_xor(v, off);
            int   oi = __shfl_xor(idx, off);
            if (ov > v || (ov == v && oi < idx)) { v = ov; idx = oi; }
        }
        if (lane == 0) {
            orienL[bgc] = idx;
            out[OUT_ORIEN + bs * BG + nt3 * 32 + bgc] = (float)idx;
        }
    }
    __syncthreads();

    const float nrm = norms[bs];

    // fp32 dot + distance: wave wv -> bgc = wv*8..+7, lane = j
    #pragma unroll
    for (int t = 0; t < 8; ++t) {
        const int bgc = wv * 8 + t;
        const int bg = nt3 * 32 + bgc;
        const int r = (lane + orienL[bgc]) & 63;
        float s = 0.f;
        #pragma unroll
        for (int h = 0; h < 4; ++h) {
            const float4* sp = (const float4*)&sat[(((size_t)bs * 4 + h) * 64 + r) * 16];
            const float4* gp = (const float4*)&grd[(((size_t)bg * 4 + h) * 64 + lane) * 16];
            #pragma unroll
            for (int c4 = 0; c4 < 4; ++c4) {
                float4 sv = sp[c4];
                float4 gv = gp[c4];
                s = fmaf(sv.x, gv.x, fmaf(sv.y, gv.y, fmaf(sv.z, gv.z, fmaf(sv.w, gv.w, s))));
            }
        }
        #pragma unroll
        for (int off = 32; off; off >>= 1) s += __shfl_xor(s, off);
        if (lane == 0)
            out[OUT_DIST + (size_t)bg * BS + bs] = 2.f - 2.f * (s / nrm);
    }
}

// ---------------- fallback (R3, verified): used only if ws too small ----------------
__device__ __forceinline__ int satIdxFB(int hw, int c4) {
    return hw * 16 + 4 * ((c4 + (hw >> 1)) & 3);
}
__device__ __forceinline__ float rot_add(int baddr, float p) {
    return __int_as_float(__builtin_amdgcn_ds_bpermute(baddr, __float_as_int(p)));
}
__device__ __forceinline__ float dot_rev(const float4 s0, const float4 s1,
                                         const float4 s2, const float4 s3,
                                         const float* __restrict__ g) {
    float p0 = fmaf(s0.x, g[15], fmaf(s0.y, g[14], fmaf(s0.z, g[13], s0.w * g[12])));
    float p1 = fmaf(s1.x, g[11], fmaf(s1.y, g[10], fmaf(s1.z, g[ 9], s1.w * g[ 8])));
    float p2 = fmaf(s2.x, g[ 7], fmaf(s2.y, g[ 6], fmaf(s2.z, g[ 5], s2.w * g[ 4])));
    float p3 = fmaf(s3.x, g[ 3], fmaf(s3.y, g[ 2], fmaf(s3.z, g[ 1], s3.w * g[ 0])));
    return (p0 + p1) + (p2 + p3);
}
#define NB 8
__global__ __launch_bounds__(256)
void pf_fused_fb(const float* __restrict__ sat, const float* __restrict__ grd,
                 float* __restrict__ out)
{
    __shared__ float satL[H * W * C];
    __shared__ float partL[NB * 4 * W];
    __shared__ float sumL[4];
    __shared__ float dotP[NB * 4];
    __shared__ int   orienL[NB];
    const int bs = blockIdx.y, bg0 = blockIdx.x * NB;
    const int tid = threadIdx.x, wv = tid >> 6, lane = tid & 63;
    const float4* sp = (const float4*)(sat + (((size_t)bs * H + wv) * W + lane) * C);
    const float4 s0 = sp[0], s1 = sp[1], s2 = sp[2], s3 = sp[3];
    { const int hw = wv * W + lane;
      *(float4*)&satL[satIdxFB(hw,0)] = s0; *(float4*)&satL[satIdxFB(hw,1)] = s1;
      *(float4*)&satL[satIdxFB(hw,2)] = s2; *(float4*)&satL[satIdxFB(hw,3)] = s3; }
    { float a = fmaf(s0.x,s0.x,fmaf(s0.y,s0.y,fmaf(s0.z,s0.z,s0.w*s0.w)));
      float b = fmaf(s1.x,s1.x,fmaf(s1.y,s1.y,fmaf(s1.z,s1.z,s1.w*s1.w)));
      float c = fmaf(s2.x,s2.x,fmaf(s2.y,s2.y,fmaf(s2.z,s2.z,s2.w*s2.w)));
      float d = fmaf(s3.x,s3.x,fmaf(s3.y,s3.y,fmaf(s3.z,s3.z,s3.w*s3.w)));
      float s = (a+b)+(c+d);
      #pragma unroll
      for (int off = 32; off; off >>= 1) s += __shfl_xor(s, off);
      if (lane == 0) sumL[wv] = s; }
    const float* gpB = grd + (size_t)(bg0 * H + wv) * W * C;
    #pragma unroll
    for (int bp = 0; bp < NB/2; ++bp) {
        const float* gA = gpB + (2*bp) * HWC;
        const float* gB2 = gpB + (2*bp+1) * HWC;
        float accA = 0.f, accB = 0.f;
        int baddr = lane << 2;
        #pragma unroll 2
        for (int j = 0; j < W; ++j) {
            float pA = dot_rev(s0,s1,s2,s3, gA + j*C);
            float pB = dot_rev(s0,s1,s2,s3, gB2 + j*C);
            accA += rot_add(baddr, pA); accB += rot_add(baddr, pB);
            baddr = (baddr + 4) & 255;
        }
        partL[((2*bp)*4 + wv)*W + lane] = accA;
        partL[((2*bp+1)*4 + wv)*W + lane] = accB;
    }
    __syncthreads();
    for (int b = wv; b < NB; b += 4) {
        float v = (partL[(b*4+0)*W+lane] + partL[(b*4+1)*W+lane])
                + (partL[(b*4+2)*W+lane] + partL[(b*4+3)*W+lane]);
        int idx = lane;
        #pragma unroll
        for (int off = 32; off; off >>= 1) {
            float ov = __shfl_xor(v, off); int oi = __shfl_xor(idx, off);
            if (ov > v || (ov == v && oi < idx)) { v = ov; idx = oi; }
        }
        if (lane == 0) { orienL[b] = idx; out[OUT_ORIEN + bs*BG + (bg0+b)] = (float)idx; }
    }
    __syncthreads();
    const float nrm = sqrtf(sumL[0]+sumL[1]+sumL[2]+sumL[3] + 1e-8f);
    { float dp[NB];
      #pragma unroll
      for (int b = 0; b < NB; ++b) {
          const int row = (lane + orienL[b]) & 63;
          const float* gRow = grd + (((size_t)(bg0+b)*H + wv)*W + lane)*C;
          float s = 0.f;
          #pragma unroll
          for (int c4 = 0; c4 < 4; ++c4) {
              float4 sv = *(const float4*)&satL[satIdxFB(wv*W+row, c4)];
              float4 gv = *(const float4*)(gRow + 4*c4);
              s = fmaf(sv.x,gv.x, fmaf(sv.y,gv.y, fmaf(sv.z,gv.z, fmaf(sv.w,gv.w, s))));
          }
          dp[b] = s;
      }
      #pragma unroll
      for (int b = 0; b < NB; ++b) {
          float s = dp[b];
          #pragma unroll
          for (int off = 32; off; off >>= 1) s += __shfl_xor(s, off);
          if (lane == 0) dotP[b*4 + wv] = s;
      } }
    __syncthreads();
    if (tid < NB) {
        float d = ((dotP[tid*4+0]+dotP[tid*4+1])+(dotP[tid*4+2]+dotP[tid*4+3])) / nrm;
        out[OUT_DIST + (size_t)(bg0+tid)*BS + bs] = 2.f - 2.f*d;
    }
}

extern "C" void kernel_launch(void* const* d_in, const int* in_sizes, int n_in,
                              void* d_out, int out_size, void* d_ws, size_t ws_size,
                              hipStream_t stream) {
    const float* sat = (const float*)d_in[0];
    const float* grd = (const float*)d_in[1];
    float* out = (float*)d_out;

    if (ws_size < WS_NEEDED) {
        hipMemcpyAsync(out,             sat, (size_t)SAT_ELEMS * sizeof(float),
                       hipMemcpyDeviceToDevice, stream);
        hipMemcpyAsync(out + SAT_ELEMS, grd, (size_t)SAT_ELEMS * sizeof(float),
                       hipMemcpyDeviceToDevice, stream);
        dim3 grid(BG / NB, BS);
        pf_fused_fb<<<grid, 256, 0, stream>>>(sat, grd, out);
        return;
    }

    unsigned short* Bpk   = (unsigned short*)d_ws;
    float*          part  = (float*)((char*)d_ws + WS_PART_OFF);
    float*          norms = (float*)((char*)d_ws + WS_NORM_OFF);
    unsigned int*   cnt   = (unsigned int*)((char*)d_ws + WS_CNT_OFF);

    pf_pack_b<<<96, 512, 0, stream>>>(sat, grd, Bpk, norms, cnt, out);
    pf_corr<<<dim3(NT3, BS, 4), 256, 0, stream>>>(sat, grd, Bpk, part, norms, cnt, out);
}

// Round 15
// 50.623 us; speedup vs baseline: 3.6240x; 3.6240x over previous
//
#include <hip/hip_runtime.h>
#include <math.h>
#include <stdint.h>

// Problem: ProcessFeatures_83296595738632
// corr[bs,bg,i] = sum_{h,j,k} sat[bs,h,(i+j)%64,k] * grd[bg,h,j,15-k]
// orien = argmax_i corr (first-max); dot with cyclic shift orien, /||sat||
// distance[bg,bs] = 2-2*dot[bs,bg]; out: sat | grd | distance | orien(float)
//
// R15 = R12 (best: 49 us) with the GEMM inner loop re-scheduled:
// 8 INDEPENDENT accumulator chains (4 mtiles x 2), MFMAs issued round-robin
// so same-chain ops are 8 slots apart (~40 cyc > MFMA dep latency).
// R12 was bound at MfmaUtil 15.7% ~= 5/32 = dependent-chain stall.

#define BS   96
#define H    4
#define W    64
#define C    16
#define BG   96
#define HWC  (H*W*C)                  // 4096

#define SAT_ELEMS (BS*H*W*C)          // 393216
#define OUT_DIST  (2*SAT_ELEMS)       // 786432
#define OUT_ORIEN (OUT_DIST + BS*BG)  // 795648

#define WS_NEEDED ((size_t)2 * SAT_ELEMS * 2)   // 1.5 MB

typedef __attribute__((ext_vector_type(4)))  short short4v;
typedef __attribute__((ext_vector_type(8)))  short short8v;
typedef __attribute__((ext_vector_type(4)))  float f32x4;

__device__ __forceinline__ void bsplit(float x, unsigned short& hi, unsigned short& lo) {
    unsigned int u = __float_as_uint(x);
    unsigned int r = (u + 0x7FFFu + ((u >> 16) & 1u)) >> 16;   // RNE to bf16
    hi = (unsigned short)r;
    float hf = __uint_as_float(r << 16);
    float l = x - hf;
    unsigned int ul = __float_as_uint(l);
    unsigned int rl = (ul + 0x7FFFu + ((ul >> 16) & 1u)) >> 16;
    lo = (unsigned short)rl;
}

// ---------------- prologue: pack B fragments (16x16x32 layout) + passthrough ----
// Fragment (j,kh,nt6,pl): lane l, elem e ->
//   B[k = (l>>4)*8+e][col = l&15] = grdR[j][nt6*16 + (l&15)][kh*32 + (l>>4)*8 + e]
//   grdR[j][bg][hk] = grd[bg][hk>>4][j][15-(hk&15)]
__global__ __launch_bounds__(512)
void pf_pack_b(const float* __restrict__ sat, const float* __restrict__ grd,
               unsigned short* __restrict__ Bpk, float* __restrict__ out)
{
    int t = blockIdx.x * 512 + threadIdx.x;    // < 49152 = 64j * 2kh * 6nt * 64lane
    int lane = t & 63;
    int f    = t >> 6;            // fragment id: ((j*2+kh)*6 + nt6)
    int nt6  = f % 6;
    int g    = f / 6;
    int kh   = g & 1;
    int j    = g >> 1;

    int col = nt6 * 16 + (lane & 15);
    int u   = lane >> 4;
    int h   = kh * 2 + (u >> 1);
    int k0  = (u & 1) * 8;        // hk = kh*32 + u*8 -> within-h offset k0

    const float* row = grd + ((size_t)(col * 4 + h) * 64 + j) * 16 + (8 - k0);
    float tmp[8];
    *(float4*)&tmp[0] = *(const float4*)(row);
    *(float4*)&tmp[4] = *(const float4*)(row + 4);

    short8v hv, lv;
    #pragma unroll
    for (int e = 0; e < 8; ++e) {
        unsigned short hi, lo;
        bsplit(tmp[7 - e], hi, lo);          // value[e] = grd[...][15-k0-e]
        hv[e] = (short)hi; lv[e] = (short)lo;
    }
    size_t base = (size_t)f << 10;           // 1024 ushorts per fragment pair
    *(short8v*)&Bpk[base + lane * 8]       = hv;   // plane 0 (hi)
    *(short8v*)&Bpk[base + 512 + lane * 8] = lv;   // plane 1 (lo)

    // passthrough copies: out[0..] = sat, out[SAT..] = grd
    const float4* s4 = (const float4*)sat;
    const float4* g4 = (const float4*)grd;
    float4* o4 = (float4*)out;
    #pragma unroll
    for (int idx = t; idx < 2 * SAT_ELEMS / 4; idx += 49152) {
        o4[idx] = (idx < SAT_ELEMS / 4) ? s4[idx] : g4[idx - SAT_ELEMS / 4];
    }
}

// ---------------- fused: corr MFMA + argmax + dot + distance ----------------
#define MFMA16(a, b, c) __builtin_amdgcn_mfma_f32_16x16x32_bf16((a), (b), (c), 0, 0, 0)

__global__ __launch_bounds__(512, 4)
void pf_fused(const float* __restrict__ sat, const float* __restrict__ grd,
              const unsigned short* __restrict__ Bpk, float* __restrict__ out)
{
    __shared__ unsigned short sHi[4096], sLo[4096];   // satM planes, swizzled (16 KB)
    __shared__ float corrPart[8][64][17];             // 34.8 KB (odd stride)
    __shared__ float redW[8];
    __shared__ int   orienL[16];

    const int bs  = blockIdx.y;
    const int nt6 = blockIdx.x;          // 16-bg group
    const int bg0 = nt6 * 16;
    const int tid = threadIdx.x;
    const int wv  = tid >> 6, lane = tid & 63;
    const int u   = lane >> 4;
    const int kq  = wv;                  // K eighth: j in [kq*8, kq*8+8)

    // ---- stage satM (swizzled bf16 hi/lo) + norm partial ----
    // satM[w][hk] = sat[bs][hk>>4][w][hk&15]; chunk cc=hk>>3 at slot cc^(w&7)
    {
        const float4* satB = (const float4*)(sat + (size_t)bs * HWC);
        float np = 0.f;
        #pragma unroll
        for (int t = tid; t < 1024; t += 512) {
            float4 v = satB[t];
            int e = 4 * t;
            int h = e >> 10, w = (e >> 4) & 63, k = e & 15;
            int cc = (h * 16 + k) >> 3;
            int dst = w * 64 + ((cc ^ (w & 7)) * 8) + (k & 7);
            short4v hvv, lvv;
            unsigned short hi, lo;
            bsplit(v.x, hi, lo); hvv[0] = hi; lvv[0] = lo;
            bsplit(v.y, hi, lo); hvv[1] = hi; lvv[1] = lo;
            bsplit(v.z, hi, lo); hvv[2] = hi; lvv[2] = lo;
            bsplit(v.w, hi, lo); hvv[3] = hi; lvv[3] = lo;
            *(short4v*)&sHi[dst] = hvv;
            *(short4v*)&sLo[dst] = lvv;
            np = fmaf(v.x, v.x, fmaf(v.y, v.y, fmaf(v.z, v.z, fmaf(v.w, v.w, np))));
        }
        #pragma unroll
        for (int off = 32; off; off >>= 1) np += __shfl_xor(np, off);
        if (lane == 0) redW[wv] = np;
    }
    __syncthreads();

    // ---- corr GEMM: bf16x4, 4 mtiles per wave, K-slice 8 j ----
    // 8 independent accumulator chains: c<m>0 = ah*bh + al*bl, c<m>1 = ah*bl + al*bh
    f32x4 c00={0.f,0.f,0.f,0.f}, c01={0.f,0.f,0.f,0.f};
    f32x4 c10={0.f,0.f,0.f,0.f}, c11={0.f,0.f,0.f,0.f};
    f32x4 c20={0.f,0.f,0.f,0.f}, c21={0.f,0.f,0.f,0.f};
    f32x4 c30={0.f,0.f,0.f,0.f}, c31={0.f,0.f,0.f,0.f};

    const int l15 = lane & 15;
    // B fragment base: fragment id f = (j*2+kh)*6 + nt6
    const unsigned short* __restrict__ bb =
        Bpk + (((size_t)(kq * 8 * 2) * 6 + nt6) << 10) + lane * 8;
    // ushort strides: per kh = 6<<10, per j = 12<<10

    #pragma unroll
    for (int jj = 0; jj < 8; ++jj) {
        const int j = kq * 8 + jj;
        const unsigned short* bj = bb + (size_t)jj * (12 << 10);
        #pragma unroll
        for (int kh = 0; kh < 2; ++kh) {
            const unsigned short* bp = bj + ((size_t)(kh * 6) << 10);
            short8v bh = *(const short8v*)bp;
            short8v bl = *(const short8v*)(bp + 512);
            const int cc = kh * 4 + u;
            // A fragments for the 4 mtiles at this (j, kh)
            const int r0 = (      l15 + j) & 63;
            const int r1 = (16 + l15 + j) & 63;
            const int r2 = (32 + l15 + j) & 63;
            const int r3 = (48 + l15 + j) & 63;
            const int a0 = (r0 << 6) + ((cc ^ (r0 & 7)) << 3);
            const int a1 = (r1 << 6) + ((cc ^ (r1 & 7)) << 3);
            const int a2 = (r2 << 6) + ((cc ^ (r2 & 7)) << 3);
            const int a3 = (r3 << 6) + ((cc ^ (r3 & 7)) << 3);
            short8v ah0 = *(const short8v*)&sHi[a0], al0 = *(const short8v*)&sLo[a0];
            short8v ah1 = *(const short8v*)&sHi[a1], al1 = *(const short8v*)&sLo[a1];
            short8v ah2 = *(const short8v*)&sHi[a2], al2 = *(const short8v*)&sLo[a2];
            short8v ah3 = *(const short8v*)&sHi[a3], al3 = *(const short8v*)&sLo[a3];
            // round 1: hi*hi -> chain0, hi*lo -> chain1  (8 indep ops)
            c00 = MFMA16(ah0, bh, c00);
            c10 = MFMA16(ah1, bh, c10);
            c20 = MFMA16(ah2, bh, c20);
            c30 = MFMA16(ah3, bh, c30);
            c01 = MFMA16(ah0, bl, c01);
            c11 = MFMA16(ah1, bl, c11);
            c21 = MFMA16(ah2, bl, c21);
            c31 = MFMA16(ah3, bl, c31);
            // round 2: lo*hi -> chain1, lo*lo -> chain0  (8 indep ops)
            c01 = MFMA16(al0, bh, c01);
            c11 = MFMA16(al1, bh, c11);
            c21 = MFMA16(al2, bh, c21);
            c31 = MFMA16(al3, bh, c31);
            c00 = MFMA16(al0, bl, c00);
            c10 = MFMA16(al1, bl, c10);
            c20 = MFMA16(al2, bl, c20);
            c30 = MFMA16(al3, bl, c30);
        }
    }

    // combine chains per mtile
    f32x4 acc0 = c00 + c01;
    f32x4 acc1 = c10 + c11;
    f32x4 acc2 = c20 + c21;
    f32x4 acc3 = c30 + c31;

    // ---- C/D -> corrPart[kq]: col = lane&15, row = m*16 + (lane>>4)*4 + reg ----
    {
        const int rr = u * 4;
        #pragma unroll
        for (int reg = 0; reg < 4; ++reg) {
            corrPart[kq][rr + reg][l15]      = acc0[reg];
            corrPart[kq][16 + rr + reg][l15] = acc1[reg];
            corrPart[kq][32 + rr + reg][l15] = acc2[reg];
            corrPart[kq][48 + rr + reg][l15] = acc3[reg];
        }
    }
    __syncthreads();

    // ---- argmax per bg (first-max tie-break): wave wv -> bgc = wv*2..+1 ----
    #pragma unroll
    for (int t = 0; t < 2; ++t) {
        const int bgc = wv * 2 + t;
        float v = ((corrPart[0][lane][bgc] + corrPart[1][lane][bgc])
                +  (corrPart[2][lane][bgc] + corrPart[3][lane][bgc]))
                + ((corrPart[4][lane][bgc] + corrPart[5][lane][bgc])
                +  (corrPart[6][lane][bgc] + corrPart[7][lane][bgc]));
        int idx = lane;
        #pragma unroll
        for (int off = 32; off; off >>= 1) {
            float ov = __shfl_xor(v, off);
            int   oi = __shfl_xor(idx, off);
            if (ov > v || (ov == v && oi < idx)) { v = ov; idx = oi; }
        }
        if (lane == 0) {
            orienL[bgc] = idx;
            out[OUT_ORIEN + bs * BG + bg0 + bgc] = (float)idx;
        }
    }
    __syncthreads();

    const float nrm = sqrtf(((redW[0] + redW[1]) + (redW[2] + redW[3]))
                          + ((redW[4] + redW[5]) + (redW[6] + redW[7])) + 1e-8f);

    // ---- fp32 dot + distance: wave wv -> bgc = wv*2..+1, lane = j ----
    #pragma unroll
    for (int t = 0; t < 2; ++t) {
        const int bgc = wv * 2 + t;
        const int bg = bg0 + bgc;
        const int r = (lane + orienL[bgc]) & 63;
        float s = 0.f;
        #pragma unroll
        for (int h = 0; h < 4; ++h) {
            const float4* sp = (const float4*)&sat[(((size_t)bs * 4 + h) * 64 + r) * 16];
            const float4* gp = (const float4*)&grd[(((size_t)bg * 4 + h) * 64 + lane) * 16];
            #pragma unroll
            for (int c4 = 0; c4 < 4; ++c4) {
                float4 sv = sp[c4];
                float4 gv = gp[c4];
                s = fmaf(sv.x, gv.x, fmaf(sv.y, gv.y, fmaf(sv.z, gv.z, fmaf(sv.w, gv.w, s))));
            }
        }
        #pragma unroll
        for (int off = 32; off; off >>= 1) s += __shfl_xor(s, off);
        if (lane == 0)
            out[OUT_DIST + (size_t)bg * BS + bs] = 2.f - 2.f * (s / nrm);
    }
}

// ---------------- fallback (R3, verified): used only if ws too small ----------------
__device__ __forceinline__ int satIdxFB(int hw, int c4) {
    return hw * 16 + 4 * ((c4 + (hw >> 1)) & 3);
}
__device__ __forceinline__ float rot_add(int baddr, float p) {
    return __int_as_float(__builtin_amdgcn_ds_bpermute(baddr, __float_as_int(p)));
}
__device__ __forceinline__ float dot_rev(const float4 s0, const float4 s1,
                                         const float4 s2, const float4 s3,
                                         const float* __restrict__ g) {
    float p0 = fmaf(s0.x, g[15], fmaf(s0.y, g[14], fmaf(s0.z, g[13], s0.w * g[12])));
    float p1 = fmaf(s1.x, g[11], fmaf(s1.y, g[10], fmaf(s1.z, g[ 9], s1.w * g[ 8])));
    float p2 = fmaf(s2.x, g[ 7], fmaf(s2.y, g[ 6], fmaf(s2.z, g[ 5], s2.w * g[ 4])));
    float p3 = fmaf(s3.x, g[ 3], fmaf(s3.y, g[ 2], fmaf(s3.z, g[ 1], s3.w * g[ 0])));
    return (p0 + p1) + (p2 + p3);
}
#define NB 8
__global__ __launch_bounds__(256)
void pf_fused_fb(const float* __restrict__ sat, const float* __restrict__ grd,
                 float* __restrict__ out)
{
    __shared__ float satL[H * W * C];
    __shared__ float partL[NB * 4 * W];
    __shared__ float sumL[4];
    __shared__ float dotP[NB * 4];
    __shared__ int   orienL[NB];
    const int bs = blockIdx.y, bg0 = blockIdx.x * NB;
    const int tid = threadIdx.x, wv = tid >> 6, lane = tid & 63;
    const float4* sp = (const float4*)(sat + (((size_t)bs * H + wv) * W + lane) * C);
    const float4 s0 = sp[0], s1 = sp[1], s2 = sp[2], s3 = sp[3];
    { const int hw = wv * W + lane;
      *(float4*)&satL[satIdxFB(hw,0)] = s0; *(float4*)&satL[satIdxFB(hw,1)] = s1;
      *(float4*)&satL[satIdxFB(hw,2)] = s2; *(float4*)&satL[satIdxFB(hw,3)] = s3; }
    { float a = fmaf(s0.x,s0.x,fmaf(s0.y,s0.y,fmaf(s0.z,s0.z,s0.w*s0.w)));
      float b = fmaf(s1.x,s1.x,fmaf(s1.y,s1.y,fmaf(s1.z,s1.z,s1.w*s1.w)));
      float c = fmaf(s2.x,s2.x,fmaf(s2.y,s2.y,fmaf(s2.z,s2.z,s2.w*s2.w)));
      float d = fmaf(s3.x,s3.x,fmaf(s3.y,s3.y,fmaf(s3.z,s3.z,s3.w*s3.w)));
      float s = (a+b)+(c+d);
      #pragma unroll
      for (int off = 32; off; off >>= 1) s += __shfl_xor(s, off);
      if (lane == 0) sumL[wv] = s; }
    const float* gpB = grd + (size_t)(bg0 * H + wv) * W * C;
    #pragma unroll
    for (int bp = 0; bp < NB/2; ++bp) {
        const float* gA = gpB + (2*bp) * HWC;
        const float* gB2 = gpB + (2*bp+1) * HWC;
        float accA = 0.f, accB = 0.f;
        int baddr = lane << 2;
        #pragma unroll 2
        for (int j = 0; j < W; ++j) {
            float pA = dot_rev(s0,s1,s2,s3, gA + j*C);
            float pB = dot_rev(s0,s1,s2,s3, gB2 + j*C);
            accA += rot_add(baddr, pA); accB += rot_add(baddr, pB);
            baddr = (baddr + 4) & 255;
        }
        partL[((2*bp)*4 + wv)*W + lane] = accA;
        partL[((2*bp+1)*4 + wv)*W + lane] = accB;
    }
    __syncthreads();
    for (int b = wv; b < NB; b += 4) {
        float v = (partL[(b*4+0)*W+lane] + partL[(b*4+1)*W+lane])
                + (partL[(b*4+2)*W+lane] + partL[(b*4+3)*W+lane]);
        int idx = lane;
        #pragma unroll
        for (int off = 32; off; off >>= 1) {
            float ov = __shfl_xor(v, off); int oi = __shfl_xor(idx, off);
            if (ov > v || (ov == v && oi < idx)) { v = ov; idx = oi; }
        }
        if (lane == 0) { orienL[b] = idx; out[OUT_ORIEN + bs*BG + (bg0+b)] = (float)idx; }
    }
    __syncthreads();
    const float nrm = sqrtf(sumL[0]+sumL[1]+sumL[2]+sumL[3] + 1e-8f);
    { float dp[NB];
      #pragma unroll
      for (int b = 0; b < NB; ++b) {
          const int row = (lane + orienL[b]) & 63;
          const float* gRow = grd + (((size_t)(bg0+b)*H + wv)*W + lane)*C;
          float s = 0.f;
          #pragma unroll
          for (int c4 = 0; c4 < 4; ++c4) {
              float4 sv = *(const float4*)&satL[satIdxFB(wv*W+row, c4)];
              float4 gv = *(const float4*)(gRow + 4*c4);
              s = fmaf(sv.x,gv.x, fmaf(sv.y,gv.y, fmaf(sv.z,gv.z, fmaf(sv.w,gv.w, s))));
          }
          dp[b] = s;
      }
      #pragma unroll
      for (int b = 0; b < NB; ++b) {
          float s = dp[b];
          #pragma unroll
          for (int off = 32; off; off >>= 1) s += __shfl_xor(s, off);
          if (lane == 0) dotP[b*4 + wv] = s;
      } }
    __syncthreads();
    if (tid < NB) {
        float d = ((dotP[tid*4+0]+dotP[tid*4+1])+(dotP[tid*4+2]+dotP[tid*4+3])) / nrm;
        out[OUT_DIST + (size_t)(bg0+tid)*BS + bs] = 2.f - 2.f*d;
    }
}

extern "C" void kernel_launch(void* const* d_in, const int* in_sizes, int n_in,
                              void* d_out, int out_size, void* d_ws, size_t ws_size,
                              hipStream_t stream) {
    const float* sat = (const float*)d_in[0];
    const float* grd = (const float*)d_in[1];
    float* out = (float*)d_out;

    if (ws_size < WS_NEEDED) {
        hipMemcpyAsync(out,             sat, (size_t)SAT_ELEMS * sizeof(float),
                       hipMemcpyDeviceToDevice, stream);
        hipMemcpyAsync(out + SAT_ELEMS, grd, (size_t)SAT_ELEMS * sizeof(float),
                       hipMemcpyDeviceToDevice, stream);
        dim3 grid(BG / NB, BS);
        pf_fused_fb<<<grid, 256, 0, stream>>>(sat, grd, out);
        return;
    }

    unsigned short* Bpk = (unsigned short*)d_ws;
    pf_pack_b<<<96, 512, 0, stream>>>(sat, grd, Bpk, out);
    pf_fused<<<dim3(6, BS), 512, 0, stream>>>(sat, grd, Bpk, out);
}